// Round 1
// baseline (1127.266 us; speedup 1.0000x reference)
//
#include <hip/hip_runtime.h>
#include <stdint.h>

// Shapes (fixed): V=32000, E=512, H=1024, A=512, L=2, B=64, S=128
#define HD    1024
#define BATCH 64
#define SEQ   128
#define AD    512
#define EMBD  512
#define VOCAB 32000

typedef float f32x4 __attribute__((ext_vector_type(4)));
typedef short bf8   __attribute__((ext_vector_type(8)));

// ---- workspace layout (floats) ----
// score    [0        , 8192)      (B*S)
// dec_proj [8192     , 40960)     (B*A)
// gates0   [40960    , 303104)    (B*4H)
// gates1   [303104   , 565248)    (B*4H)
// x0       [565248   , 729088)    (B*2560)  [emb | context]
// xfc      [729088   , 925696)    (B*3072)  [h1 | context]
// h0       [925696   , 991232)    (B*H)
#define WS_SCORE  0
#define WS_DECP   8192
#define WS_G0     40960
#define WS_G1     303104
#define WS_X0     565248
#define WS_XFC    729088
#define WS_H0     925696
#define ZERO_F4S  141312   // floats 0..565248 zeroed as float4 (score+dec_proj+gates0+gates1)

// output layout (floats)
#define OUT_LOGITS 0
#define OUT_HID    2048000
#define OUT_CELL   2179072
#define OUT_ALPHA  2310144

__device__ __forceinline__ short f2bf(float f) {
  uint32_t u = __float_as_uint(f);
  u += 0x7FFF + ((u >> 16) & 1);   // RNE
  return (short)(u >> 16);
}

__device__ __forceinline__ void store_bf4(short* p, float4 v) {
  short4 s;
  s.x = f2bf(v.x); s.y = f2bf(v.y); s.z = f2bf(v.z); s.w = f2bf(v.w);
  *(short4*)p = s;
}

// ---------------------------------------------------------------------------
// k_init: zero score/dec_proj/gates0/gates1 + gather embedding into x0[:, 0:512]
// grid: 552 zero blocks + 32 gather blocks = 584, 256 thr
// ---------------------------------------------------------------------------
__global__ __launch_bounds__(256) void k_init(float* __restrict__ ws,
                                              const int* __restrict__ token,
                                              const float* __restrict__ emb) {
  int bid = blockIdx.x;
  if (bid < 552) {
    int i = bid * 256 + threadIdx.x;        // float4 index < 141312
    *(float4*)&ws[(size_t)i * 4] = make_float4(0.f, 0.f, 0.f, 0.f);
  } else {
    int idx = (bid - 552) * 256 + threadIdx.x;   // 0..8191 (B * 128 f4/row)
    int b = idx >> 7, e4 = idx & 127;
    int tok = token[b];
    float4 v = *(const float4*)&emb[(size_t)tok * EMBD + e4 * 4];
    *(float4*)&ws[WS_X0 + (size_t)b * 2560 + e4 * 4] = v;
  }
}

// ---------------------------------------------------------------------------
// gemm_thin: C(64 x N) (+)= A(64 x K) @ B^T(N x K), bf16 MFMA, fp32 acc.
// Tile: M=64, N=64, K=64. 256 thr = 4 waves; wave w owns rows [16w,16w+16).
// DIRECT: write C = acc + bias (single K chunk). else atomicAdd partials.
// grid: (N/64, 1, K/k_chunk)
// ---------------------------------------------------------------------------
template <bool DIRECT>
__global__ __launch_bounds__(256) void gemm_thin(
    const float* __restrict__ A, int a_stride,
    const float* __restrict__ Bm,   // N x K row-major
    float* __restrict__ C, int ldc,
    const float* __restrict__ bias,
    int K_total, int k_chunk) {
  __shared__ __align__(16) short As[64][72];
  __shared__ __align__(16) short Bs[64][72];
  const int tid = threadIdx.x;
  const int wave = tid >> 6, lane = tid & 63;
  const int quad = lane >> 4, l16 = lane & 15;
  const int n0 = blockIdx.x * 64;
  const int k0 = blockIdx.z * k_chunk;
  int kend = k0 + k_chunk; if (kend > K_total) kend = K_total;
  const int srow = tid >> 4, sc4 = (tid & 15) * 4;

  f32x4 acc[4];
#pragma unroll
  for (int i = 0; i < 4; ++i) acc[i] = (f32x4){0.f, 0.f, 0.f, 0.f};

  for (int kt = k0; kt < kend; kt += 64) {
#pragma unroll
    for (int p = 0; p < 4; ++p) {
      int row = srow + p * 16;
      float4 av = *(const float4*)&A[(size_t)row * a_stride + kt + sc4];
      float4 bv = *(const float4*)&Bm[(size_t)(n0 + row) * K_total + kt + sc4];
      store_bf4(&As[row][sc4], av);
      store_bf4(&Bs[row][sc4], bv);
    }
    __syncthreads();
#pragma unroll
    for (int kk = 0; kk < 64; kk += 32) {
      bf8 af = *(const bf8*)&As[wave * 16 + l16][kk + quad * 8];
#pragma unroll
      for (int ns = 0; ns < 4; ++ns) {
        bf8 bf = *(const bf8*)&Bs[ns * 16 + l16][kk + quad * 8];
        acc[ns] = __builtin_amdgcn_mfma_f32_16x16x32_bf16(af, bf, acc[ns], 0, 0, 0);
      }
    }
    __syncthreads();
  }

#pragma unroll
  for (int ns = 0; ns < 4; ++ns) {
    int n = n0 + ns * 16 + l16;
#pragma unroll
    for (int r = 0; r < 4; ++r) {
      int m = wave * 16 + quad * 4 + r;
      if (DIRECT) {
        C[(size_t)m * ldc + n] = acc[ns][r] + (bias ? bias[n] : 0.f);
      } else {
        atomicAdd(&C[(size_t)m * ldc + n], acc[ns][r]);
      }
    }
  }
}

// ---------------------------------------------------------------------------
// k_attn: fused enc_proj GEMM + tanh + v-dot, atomicAdd partial scores.
// energy[b,s,a] = tanh( enc_t[b,s,:] . W_enc[a,:] + dec_proj[b,a] )
// score[b,s] += sum_a v[a] * energy
// A rows: enc_out[(s0+i)*B + b][:], row stride B*2H. Tile M=64 x N=128.
// grid: (128 mblk, 4 nblk), 256 thr.
// ---------------------------------------------------------------------------
__global__ __launch_bounds__(256) void k_attn(
    const float* __restrict__ enc, const float* __restrict__ Wenc,
    const float* __restrict__ dec_proj, const float* __restrict__ vw,
    float* __restrict__ score) {
  __shared__ __align__(16) short As[64][72];
  __shared__ __align__(16) short Bs[128][72];
  const int tid = threadIdx.x;
  const int wave = tid >> 6, lane = tid & 63;
  const int quad = lane >> 4, l16 = lane & 15;
  const int mblk = blockIdx.x, nblk = blockIdx.y;
  const int b = mblk >> 1, s0 = (mblk & 1) * 64;
  const int n0 = nblk * 128;
  const size_t abase = ((size_t)s0 * BATCH + b) * 2048;
  const int srow = tid >> 4, sc4 = (tid & 15) * 4;

  f32x4 acc[8];
#pragma unroll
  for (int i = 0; i < 8; ++i) acc[i] = (f32x4){0.f, 0.f, 0.f, 0.f};

  for (int kt = 0; kt < 2048; kt += 64) {
#pragma unroll
    for (int p = 0; p < 4; ++p) {
      int row = srow + p * 16;
      float4 av = *(const float4*)&enc[abase + (size_t)row * (BATCH * 2048) + kt + sc4];
      store_bf4(&As[row][sc4], av);
    }
#pragma unroll
    for (int p = 0; p < 8; ++p) {
      int row = srow + p * 16;
      float4 bv = *(const float4*)&Wenc[(size_t)(n0 + row) * 2048 + kt + sc4];
      store_bf4(&Bs[row][sc4], bv);
    }
    __syncthreads();
#pragma unroll
    for (int kk = 0; kk < 64; kk += 32) {
      bf8 af = *(const bf8*)&As[wave * 16 + l16][kk + quad * 8];
#pragma unroll
      for (int ns = 0; ns < 8; ++ns) {
        bf8 bf = *(const bf8*)&Bs[ns * 16 + l16][kk + quad * 8];
        acc[ns] = __builtin_amdgcn_mfma_f32_16x16x32_bf16(af, bf, acc[ns], 0, 0, 0);
      }
    }
    __syncthreads();
  }

  // epilogue: per output row, sum over this block's 128 n of v[n]*tanh(e+dp)
  float part[4] = {0.f, 0.f, 0.f, 0.f};
#pragma unroll
  for (int ns = 0; ns < 8; ++ns) {
    int n = n0 + ns * 16 + l16;
    float dp = dec_proj[b * AD + n];
    float vv = vw[n];
#pragma unroll
    for (int r = 0; r < 4; ++r) part[r] += tanhf(acc[ns][r] + dp) * vv;
  }
#pragma unroll
  for (int r = 0; r < 4; ++r) {
    float v = part[r];
    v += __shfl_xor(v, 1);
    v += __shfl_xor(v, 2);
    v += __shfl_xor(v, 4);
    v += __shfl_xor(v, 8);
    if (l16 == 0)
      atomicAdd(&score[mblk * 64 + wave * 16 + quad * 4 + r], v);
  }
}

// ---------------------------------------------------------------------------
// k_softmax_ctx: per (b, dchunk): softmax over S=128; write alpha (dchunk 0);
// context[b, d] = sum_s alpha * enc_t[b,s,d]  -> x0[b,512+d] and xfc[b,1024+d]
// grid: (64, 4), 256 thr; each thread: one float2 of d (512 d per block).
// ---------------------------------------------------------------------------
__global__ __launch_bounds__(256) void k_softmax_ctx(
    const float* __restrict__ score, const float* __restrict__ enc,
    float* __restrict__ alpha_out, float* __restrict__ x0,
    float* __restrict__ xfc) {
  const int b = blockIdx.x, dchunk = blockIdx.y, t = threadIdx.x;
  __shared__ float al[128];
  __shared__ float buf[128];
  float sv = 0.f;
  if (t < 128) { sv = score[b * SEQ + t]; buf[t] = sv; }
  __syncthreads();
  for (int off = 64; off > 0; off >>= 1) {
    if (t < off) buf[t] = fmaxf(buf[t], buf[t + off]);
    __syncthreads();
  }
  float mx = buf[0];
  __syncthreads();
  float e = 0.f;
  if (t < 128) { e = __expf(sv - mx); buf[t] = e; }
  __syncthreads();
  for (int off = 64; off > 0; off >>= 1) {
    if (t < off) buf[t] += buf[t + off];
    __syncthreads();
  }
  float inv = 1.f / buf[0];
  if (t < 128) {
    float a = e * inv;
    al[t] = a;
    if (dchunk == 0) alpha_out[b * SEQ + t] = a;
  }
  __syncthreads();

  const int d = dchunk * 512 + t * 2;
  float2 acc = make_float2(0.f, 0.f);
#pragma unroll 4
  for (int s = 0; s < SEQ; ++s) {
    float2 ev = *(const float2*)&enc[((size_t)s * BATCH + b) * 2048 + d];
    float w = al[s];
    acc.x += w * ev.x;
    acc.y += w * ev.y;
  }
  *(float2*)&x0[(size_t)b * 2560 + 512 + d] = acc;
  *(float2*)&xfc[(size_t)b * 3072 + 1024 + d] = acc;
}

// ---------------------------------------------------------------------------
// k_act: LSTM cell elementwise. gates (B x 4H) pre-bias; PyTorch order i,f,g,o.
// grid 256 x 256 (one thread per (b,n)).
// hdst: h0 scratch (stride 1024) for layer0, xfc (stride 3072) for layer1.
// ---------------------------------------------------------------------------
__global__ __launch_bounds__(256) void k_act(
    const float* __restrict__ gates,
    const float* __restrict__ b_ih, const float* __restrict__ b_hh,
    const float* __restrict__ cell_in,
    float* __restrict__ hid_out, float* __restrict__ cell_out,
    float* __restrict__ hdst, int hstride) {
  int idx = blockIdx.x * 256 + threadIdx.x;   // < 65536
  int b = idx >> 10, n = idx & 1023;
  const float* g = gates + (size_t)b * 4096;
  float gi = g[n]          + b_ih[n]          + b_hh[n];
  float gf = g[1024 + n]   + b_ih[1024 + n]   + b_hh[1024 + n];
  float gg = g[2048 + n]   + b_ih[2048 + n]   + b_hh[2048 + n];
  float go = g[3072 + n]   + b_ih[3072 + n]   + b_hh[3072 + n];
  float i = 1.f / (1.f + __expf(-gi));
  float f = 1.f / (1.f + __expf(-gf));
  float o = 1.f / (1.f + __expf(-go));
  float c = f * cell_in[idx] + i * tanhf(gg);
  float h = o * tanhf(c);
  cell_out[idx] = c;
  hid_out[idx] = h;
  hdst[(size_t)b * hstride + n] = h;
}

// ---------------------------------------------------------------------------
extern "C" void kernel_launch(void* const* d_in, const int* in_sizes, int n_in,
                              void* d_out, int out_size, void* d_ws, size_t ws_size,
                              hipStream_t stream) {
  const int*   token  = (const int*)d_in[0];
  const float* hidden = (const float*)d_in[1];   // (2,64,1024)
  const float* cell   = (const float*)d_in[2];   // (2,64,1024)
  const float* enc    = (const float*)d_in[3];   // (128,64,2048)
  const float* emb    = (const float*)d_in[4];   // (32000,512)
  const float* W_enc  = (const float*)d_in[5];   // (512,2048)
  const float* W_dec  = (const float*)d_in[6];   // (512,1024)
  const float* v_w    = (const float*)d_in[7];   // (512,)
  const float* W_ih0  = (const float*)d_in[8];   // (4096,2560)
  const float* W_hh0  = (const float*)d_in[9];   // (4096,1024)
  const float* b_ih0  = (const float*)d_in[10];
  const float* b_hh0  = (const float*)d_in[11];
  const float* W_ih1  = (const float*)d_in[12];  // (4096,1024)
  const float* W_hh1  = (const float*)d_in[13];  // (4096,1024)
  const float* b_ih1  = (const float*)d_in[14];
  const float* b_hh1  = (const float*)d_in[15];
  const float* fc_W   = (const float*)d_in[16];  // (32000,3072)
  const float* fc_b   = (const float*)d_in[17];

  float* out = (float*)d_out;
  float* ws  = (float*)d_ws;

  float* score    = ws + WS_SCORE;
  float* dec_proj = ws + WS_DECP;
  float* gates0   = ws + WS_G0;
  float* gates1   = ws + WS_G1;
  float* x0       = ws + WS_X0;
  float* xfc      = ws + WS_XFC;
  float* h0       = ws + WS_H0;

  // 1. zero scratch + embedding gather (into x0[:, :512])
  k_init<<<584, 256, 0, stream>>>(ws, token, emb);

  // 2. dec_proj = hidden[1] @ W_dec^T  (64x512, K=1024)
  gemm_thin<false><<<dim3(8, 1, 2), 256, 0, stream>>>(
      hidden + BATCH * HD, HD, W_dec, dec_proj, AD, nullptr, 1024, 512);

  // 3. fused enc_proj + tanh + v-dot -> score (atomic partials)
  k_attn<<<dim3(128, 4), 256, 0, stream>>>(enc, W_enc, dec_proj, v_w, score);

  // 4. softmax + context (writes alpha out, x0 ctx part, xfc ctx part)
  k_softmax_ctx<<<dim3(64, 4), 256, 0, stream>>>(score, enc, out + OUT_ALPHA, x0, xfc);

  // 5-6. gates0 = x0 @ W_ih0^T + hidden[0] @ W_hh0^T
  gemm_thin<false><<<dim3(64, 1, 5), 256, 0, stream>>>(
      x0, 2560, W_ih0, gates0, 4096, nullptr, 2560, 512);
  gemm_thin<false><<<dim3(64, 1, 2), 256, 0, stream>>>(
      hidden, HD, W_hh0, gates0, 4096, nullptr, 1024, 512);

  // 7. LSTM cell 0 -> out hidden[0]/cell[0], h0 scratch
  k_act<<<256, 256, 0, stream>>>(gates0, b_ih0, b_hh0, cell,
                                 out + OUT_HID, out + OUT_CELL, h0, HD);

  // 8-9. gates1 = h0 @ W_ih1^T + hidden[1] @ W_hh1^T
  gemm_thin<false><<<dim3(64, 1, 2), 256, 0, stream>>>(
      h0, HD, W_ih1, gates1, 4096, nullptr, 1024, 512);
  gemm_thin<false><<<dim3(64, 1, 2), 256, 0, stream>>>(
      hidden + BATCH * HD, HD, W_hh1, gates1, 4096, nullptr, 1024, 512);

  // 10. LSTM cell 1 -> out hidden[1]/cell[1], h1 into xfc[:, :1024]
  k_act<<<256, 256, 0, stream>>>(gates1, b_ih1, b_hh1, cell + BATCH * HD,
                                 out + OUT_HID + BATCH * HD,
                                 out + OUT_CELL + BATCH * HD, xfc, 3072);

  // 11. logits = xfc @ fc_W^T + fc_b  (direct write)
  gemm_thin<true><<<dim3(500, 1, 1), 256, 0, stream>>>(
      xfc, 3072, fc_W, out + OUT_LOGITS, VOCAB, fc_b, 3072, 3072);
}

// Round 2
// 763.910 us; speedup vs baseline: 1.4757x; 1.4757x over previous
//
#include <hip/hip_runtime.h>
#include <stdint.h>

// Shapes (fixed): V=32000, E=512, H=1024, A=512, L=2, B=64, S=128
#define HD    1024
#define BATCH 64
#define SEQ   128
#define AD    512
#define EMBD  512
#define VOCAB 32000

typedef float f32x4 __attribute__((ext_vector_type(4)));
typedef short bf8   __attribute__((ext_vector_type(8)));

// ---- workspace layout (floats) ----
#define WS_SCOREP 0          // 4 x (64*128)  = 32768 score partial slabs
#define WS_DECP   32768      // 64*512        = 32768
#define WS_G0     65536      // 4 x (64*4096) = 1048576 gate partial slabs L0
#define WS_G1     1114112    // 4 x (64*4096) = 1048576 gate partial slabs L1
#define WS_X0     2162688    // 64*2560 [emb | context]
#define WS_XFC    2326528    // 64*3072 [h1 | context]
#define WS_H0     2523136    // 64*1024

// output layout (floats)
#define OUT_LOGITS 0
#define OUT_HID    2048000
#define OUT_CELL   2179072
#define OUT_ALPHA  2310144

__device__ __forceinline__ short f2bf(float f) {
  uint32_t u = __float_as_uint(f);
  u += 0x7FFF + ((u >> 16) & 1);   // RNE
  return (short)(u >> 16);
}

__device__ __forceinline__ void store_bf4(short* p, float4 v) {
  short4 s;
  s.x = f2bf(v.x); s.y = f2bf(v.y); s.z = f2bf(v.z); s.w = f2bf(v.w);
  *(short4*)p = s;
}

// ---------------------------------------------------------------------------
// k_init: gather embedding rows into x0[:, 0:512]. grid 32 x 256.
// ---------------------------------------------------------------------------
__global__ __launch_bounds__(256) void k_init(float* __restrict__ ws,
                                              const int* __restrict__ token,
                                              const float* __restrict__ emb) {
  int idx = blockIdx.x * 256 + threadIdx.x;   // 0..8191 (B * 128 f4/row)
  int b = idx >> 7, e4 = idx & 127;
  int tok = token[b];
  float4 v = *(const float4*)&emb[(size_t)tok * EMBD + e4 * 4];
  *(float4*)&ws[WS_X0 + (size_t)b * 2560 + e4 * 4] = v;
}

// ---------------------------------------------------------------------------
// gemm_thin: C(64 x N) = A(64 x K) @ B^T(N x K) [+ bias], bf16 MFMA, fp32 acc.
// Tile M=64,N=64,K=64; 4 waves; register-prefetch double buffer; direct write.
// grid: (N/64, 1, 1)
// ---------------------------------------------------------------------------
__global__ __launch_bounds__(256) void gemm_thin(
    const float* __restrict__ A, int a_stride,
    const float* __restrict__ Bm,   // N x K row-major
    float* __restrict__ C, int ldc,
    const float* __restrict__ bias,
    int K_total) {
  __shared__ __align__(16) short As[64][72];
  __shared__ __align__(16) short Bs[64][72];
  const int tid = threadIdx.x;
  const int wave = tid >> 6, lane = tid & 63;
  const int quad = lane >> 4, l16 = lane & 15;
  const int n0 = blockIdx.x * 64;
  const int srow = tid >> 4, sc4 = (tid & 15) * 4;

  f32x4 acc[4];
#pragma unroll
  for (int i = 0; i < 4; ++i) acc[i] = (f32x4){0.f, 0.f, 0.f, 0.f};

  float4 pa[4], pb[4];
#pragma unroll
  for (int p = 0; p < 4; ++p) {
    int row = srow + p * 16;
    pa[p] = *(const float4*)&A[(size_t)row * a_stride + sc4];
    pb[p] = *(const float4*)&Bm[(size_t)(n0 + row) * K_total + sc4];
  }

  for (int kt = 0; kt < K_total; kt += 64) {
#pragma unroll
    for (int p = 0; p < 4; ++p) {
      int row = srow + p * 16;
      store_bf4(&As[row][sc4], pa[p]);
      store_bf4(&Bs[row][sc4], pb[p]);
    }
    __syncthreads();
    if (kt + 64 < K_total) {
      int kn = kt + 64;
#pragma unroll
      for (int p = 0; p < 4; ++p) {
        int row = srow + p * 16;
        pa[p] = *(const float4*)&A[(size_t)row * a_stride + kn + sc4];
        pb[p] = *(const float4*)&Bm[(size_t)(n0 + row) * K_total + kn + sc4];
      }
    }
#pragma unroll
    for (int kk = 0; kk < 64; kk += 32) {
      bf8 af = *(const bf8*)&As[wave * 16 + l16][kk + quad * 8];
#pragma unroll
      for (int ns = 0; ns < 4; ++ns) {
        bf8 bf = *(const bf8*)&Bs[ns * 16 + l16][kk + quad * 8];
        acc[ns] = __builtin_amdgcn_mfma_f32_16x16x32_bf16(af, bf, acc[ns], 0, 0, 0);
      }
    }
    __syncthreads();
  }

#pragma unroll
  for (int ns = 0; ns < 4; ++ns) {
    int n = n0 + ns * 16 + l16;
    float bv = bias ? bias[n] : 0.f;
#pragma unroll
    for (int r = 0; r < 4; ++r) {
      int m = wave * 16 + quad * 4 + r;
      C[(size_t)m * ldc + n] = acc[ns][r] + bv;
    }
  }
}

// ---------------------------------------------------------------------------
// gemm2: Cslab[z] (64 x 4096) = partial of A1@B1^T + A2@B2^T over virtual K.
// Virtual K axis = [0,K1) from (A1,B1), [K1,K1+K2) from (A2,B2).
// grid (64, 1, ZSLABS); tiles_pz tiles of 64 per z-slab. Direct write, no atomics.
// ---------------------------------------------------------------------------
__global__ __launch_bounds__(256) void gemm2(
    const float* __restrict__ A1, int s1, int K1, const float* __restrict__ B1,
    const float* __restrict__ A2, int s2, int K2, const float* __restrict__ B2,
    float* __restrict__ Cslab, int tiles_pz) {
  __shared__ __align__(16) short As[64][72];
  __shared__ __align__(16) short Bs[64][72];
  const int tid = threadIdx.x;
  const int wave = tid >> 6, lane = tid & 63;
  const int quad = lane >> 4, l16 = lane & 15;
  const int n0 = blockIdx.x * 64;
  const int z = blockIdx.z;
  const int t0 = z * tiles_pz;
  const int srow = tid >> 4, sc4 = (tid & 15) * 4;

  f32x4 acc[4];
#pragma unroll
  for (int i = 0; i < 4; ++i) acc[i] = (f32x4){0.f, 0.f, 0.f, 0.f};

  float4 pa[4], pb[4];
  auto loadAB = [&](int tile) {
    int kv = tile * 64;
    const float* Ap; const float* Bp; int as, ks, ko;
    if (kv < K1) { Ap = A1; Bp = B1; as = s1; ks = K1; ko = kv; }
    else         { Ap = A2; Bp = B2; as = s2; ks = K2; ko = kv - K1; }
#pragma unroll
    for (int p = 0; p < 4; ++p) {
      int row = srow + p * 16;
      pa[p] = *(const float4*)&Ap[(size_t)row * as + ko + sc4];
      pb[p] = *(const float4*)&Bp[(size_t)(n0 + row) * ks + ko + sc4];
    }
  };

  loadAB(t0);
  for (int ti = t0; ti < t0 + tiles_pz; ++ti) {
#pragma unroll
    for (int p = 0; p < 4; ++p) {
      int row = srow + p * 16;
      store_bf4(&As[row][sc4], pa[p]);
      store_bf4(&Bs[row][sc4], pb[p]);
    }
    __syncthreads();
    if (ti + 1 < t0 + tiles_pz) loadAB(ti + 1);
#pragma unroll
    for (int kk = 0; kk < 64; kk += 32) {
      bf8 af = *(const bf8*)&As[wave * 16 + l16][kk + quad * 8];
#pragma unroll
      for (int ns = 0; ns < 4; ++ns) {
        bf8 bf = *(const bf8*)&Bs[ns * 16 + l16][kk + quad * 8];
        acc[ns] = __builtin_amdgcn_mfma_f32_16x16x32_bf16(af, bf, acc[ns], 0, 0, 0);
      }
    }
    __syncthreads();
  }

  float* C = Cslab + (size_t)z * (64 * 4096);
#pragma unroll
  for (int ns = 0; ns < 4; ++ns) {
    int n = n0 + ns * 16 + l16;
#pragma unroll
    for (int r = 0; r < 4; ++r) {
      int m = wave * 16 + quad * 4 + r;
      C[(size_t)m * 4096 + n] = acc[ns][r];
    }
  }
}

// ---------------------------------------------------------------------------
// k_attn: fused enc_proj GEMM + tanh + v-dot -> score partial slabs (no atomics)
// scorep[nblk][b*128 + s] = sum_{a in nblk slab} v[a]*tanh(enc.Wenc + dec_proj)
// grid (128 mblk, 4 nblk), 256 thr. Tile M=64 x N=128, reg-prefetch.
// ---------------------------------------------------------------------------
__global__ __launch_bounds__(256) void k_attn(
    const float* __restrict__ enc, const float* __restrict__ Wenc,
    const float* __restrict__ dec_proj, const float* __restrict__ vw,
    float* __restrict__ scorep) {
  __shared__ __align__(16) short As[64][72];
  __shared__ __align__(16) short Bs[128][72];
  const int tid = threadIdx.x;
  const int wave = tid >> 6, lane = tid & 63;
  const int quad = lane >> 4, l16 = lane & 15;
  const int mblk = blockIdx.x, nblk = blockIdx.y;
  const int b = mblk >> 1, s0 = (mblk & 1) * 64;
  const int n0 = nblk * 128;
  const size_t abase = ((size_t)s0 * BATCH + b) * 2048;
  const int srow = tid >> 4, sc4 = (tid & 15) * 4;

  f32x4 acc[8];
#pragma unroll
  for (int i = 0; i < 8; ++i) acc[i] = (f32x4){0.f, 0.f, 0.f, 0.f};

  float4 pa[4], pb[8];
  auto loadAB = [&](int kt) {
#pragma unroll
    for (int p = 0; p < 4; ++p) {
      int row = srow + p * 16;
      pa[p] = *(const float4*)&enc[abase + (size_t)row * (BATCH * 2048) + kt + sc4];
    }
#pragma unroll
    for (int p = 0; p < 8; ++p) {
      int row = srow + p * 16;
      pb[p] = *(const float4*)&Wenc[(size_t)(n0 + row) * 2048 + kt + sc4];
    }
  };

  loadAB(0);
  for (int kt = 0; kt < 2048; kt += 64) {
#pragma unroll
    for (int p = 0; p < 4; ++p) store_bf4(&As[srow + p * 16][sc4], pa[p]);
#pragma unroll
    for (int p = 0; p < 8; ++p) store_bf4(&Bs[srow + p * 16][sc4], pb[p]);
    __syncthreads();
    if (kt + 64 < 2048) loadAB(kt + 64);
#pragma unroll
    for (int kk = 0; kk < 64; kk += 32) {
      bf8 af = *(const bf8*)&As[wave * 16 + l16][kk + quad * 8];
#pragma unroll
      for (int ns = 0; ns < 8; ++ns) {
        bf8 bf = *(const bf8*)&Bs[ns * 16 + l16][kk + quad * 8];
        acc[ns] = __builtin_amdgcn_mfma_f32_16x16x32_bf16(af, bf, acc[ns], 0, 0, 0);
      }
    }
    __syncthreads();
  }

  float part[4] = {0.f, 0.f, 0.f, 0.f};
#pragma unroll
  for (int ns = 0; ns < 8; ++ns) {
    int n = n0 + ns * 16 + l16;
    float dp = dec_proj[b * AD + n];
    float vv = vw[n];
#pragma unroll
    for (int r = 0; r < 4; ++r) part[r] += tanhf(acc[ns][r] + dp) * vv;
  }
#pragma unroll
  for (int r = 0; r < 4; ++r) {
    float v = part[r];
    v += __shfl_xor(v, 1);
    v += __shfl_xor(v, 2);
    v += __shfl_xor(v, 4);
    v += __shfl_xor(v, 8);
    if (l16 == 0)
      scorep[nblk * (BATCH * SEQ) + mblk * 64 + wave * 16 + quad * 4 + r] = v;
  }
}

// ---------------------------------------------------------------------------
// k_softmax_ctx: sum 4 score slabs, softmax over S=128, write alpha;
// context -> x0[b,512+d], xfc[b,1024+d]. grid (64, 2), 256 thr, float4.
// ---------------------------------------------------------------------------
__global__ __launch_bounds__(256) void k_softmax_ctx(
    const float* __restrict__ scorep, const float* __restrict__ enc,
    float* __restrict__ alpha_out, float* __restrict__ x0,
    float* __restrict__ xfc) {
  const int b = blockIdx.x, dchunk = blockIdx.y, t = threadIdx.x;
  __shared__ float al[128];
  __shared__ float buf[128];
  float sv = 0.f;
  if (t < 128) {
    sv = scorep[b * SEQ + t] + scorep[8192 + b * SEQ + t]
       + scorep[16384 + b * SEQ + t] + scorep[24576 + b * SEQ + t];
    buf[t] = sv;
  }
  __syncthreads();
  for (int off = 64; off > 0; off >>= 1) {
    if (t < off) buf[t] = fmaxf(buf[t], buf[t + off]);
    __syncthreads();
  }
  float mx = buf[0];
  __syncthreads();
  float e = 0.f;
  if (t < 128) { e = __expf(sv - mx); buf[t] = e; }
  __syncthreads();
  for (int off = 64; off > 0; off >>= 1) {
    if (t < off) buf[t] += buf[t + off];
    __syncthreads();
  }
  float inv = 1.f / buf[0];
  if (t < 128) {
    float a = e * inv;
    al[t] = a;
    if (dchunk == 0) alpha_out[b * SEQ + t] = a;
  }
  __syncthreads();

  const int d = dchunk * 1024 + t * 4;
  float4 acc = make_float4(0.f, 0.f, 0.f, 0.f);
#pragma unroll 4
  for (int s = 0; s < SEQ; ++s) {
    float4 ev = *(const float4*)&enc[((size_t)s * BATCH + b) * 2048 + d];
    float w = al[s];
    acc.x += w * ev.x; acc.y += w * ev.y;
    acc.z += w * ev.z; acc.w += w * ev.w;
  }
  *(float4*)&x0[(size_t)b * 2560 + 512 + d] = acc;
  *(float4*)&xfc[(size_t)b * 3072 + 1024 + d] = acc;
}

// ---------------------------------------------------------------------------
// k_act: LSTM cell elementwise over 4 gate partial slabs + biases.
// grid 256 x 256 (one thread per (b,n)). PyTorch gate order i,f,g,o.
// ---------------------------------------------------------------------------
__global__ __launch_bounds__(256) void k_act(
    const float* __restrict__ gslab,
    const float* __restrict__ b_ih, const float* __restrict__ b_hh,
    const float* __restrict__ cell_in,
    float* __restrict__ hid_out, float* __restrict__ cell_out,
    float* __restrict__ hdst, int hstride) {
  int idx = blockIdx.x * 256 + threadIdx.x;   // < 65536
  int b = idx >> 10, n = idx & 1023;
  float gi = b_ih[n]        + b_hh[n];
  float gf = b_ih[1024 + n] + b_hh[1024 + n];
  float gg = b_ih[2048 + n] + b_hh[2048 + n];
  float go = b_ih[3072 + n] + b_hh[3072 + n];
#pragma unroll
  for (int sl = 0; sl < 4; ++sl) {
    const float* g = gslab + (size_t)sl * (64 * 4096) + (size_t)b * 4096;
    gi += g[n];
    gf += g[1024 + n];
    gg += g[2048 + n];
    go += g[3072 + n];
  }
  float i = 1.f / (1.f + __expf(-gi));
  float f = 1.f / (1.f + __expf(-gf));
  float o = 1.f / (1.f + __expf(-go));
  float c = f * cell_in[idx] + i * tanhf(gg);
  float h = o * tanhf(c);
  cell_out[idx] = c;
  hid_out[idx] = h;
  hdst[(size_t)b * hstride + n] = h;
}

// ---------------------------------------------------------------------------
extern "C" void kernel_launch(void* const* d_in, const int* in_sizes, int n_in,
                              void* d_out, int out_size, void* d_ws, size_t ws_size,
                              hipStream_t stream) {
  const int*   token  = (const int*)d_in[0];
  const float* hidden = (const float*)d_in[1];   // (2,64,1024)
  const float* cell   = (const float*)d_in[2];   // (2,64,1024)
  const float* enc    = (const float*)d_in[3];   // (128,64,2048)
  const float* emb    = (const float*)d_in[4];   // (32000,512)
  const float* W_enc  = (const float*)d_in[5];   // (512,2048)
  const float* W_dec  = (const float*)d_in[6];   // (512,1024)
  const float* v_w    = (const float*)d_in[7];   // (512,)
  const float* W_ih0  = (const float*)d_in[8];   // (4096,2560)
  const float* W_hh0  = (const float*)d_in[9];   // (4096,1024)
  const float* b_ih0  = (const float*)d_in[10];
  const float* b_hh0  = (const float*)d_in[11];
  const float* W_ih1  = (const float*)d_in[12];  // (4096,1024)
  const float* W_hh1  = (const float*)d_in[13];  // (4096,1024)
  const float* b_ih1  = (const float*)d_in[14];
  const float* b_hh1  = (const float*)d_in[15];
  const float* fc_W   = (const float*)d_in[16];  // (32000,3072)
  const float* fc_b   = (const float*)d_in[17];

  float* out = (float*)d_out;
  float* ws  = (float*)d_ws;

  float* scorep   = ws + WS_SCOREP;
  float* dec_proj = ws + WS_DECP;
  float* gates0   = ws + WS_G0;
  float* gates1   = ws + WS_G1;
  float* x0       = ws + WS_X0;
  float* xfc      = ws + WS_XFC;
  float* h0       = ws + WS_H0;

  // 1. embedding gather (into x0[:, :512])
  k_init<<<32, 256, 0, stream>>>(ws, token, emb);

  // 2. dec_proj = hidden[1] @ W_dec^T  (64x512, K=1024), direct write
  gemm_thin<<<dim3(8, 1, 1), 256, 0, stream>>>(
      hidden + BATCH * HD, HD, W_dec, dec_proj, AD, nullptr, 1024);

  // 3. fused enc_proj + tanh + v-dot -> score partial slabs
  k_attn<<<dim3(128, 4), 256, 0, stream>>>(enc, W_enc, dec_proj, v_w, scorep);

  // 4. softmax + context (writes alpha out, x0 ctx part, xfc ctx part)
  k_softmax_ctx<<<dim3(64, 2), 256, 0, stream>>>(scorep, enc, out + OUT_ALPHA, x0, xfc);

  // 5. gates0 slabs = x0 @ W_ih0^T + hidden[0] @ W_hh0^T (virtual K=3584, 56 tiles)
  gemm2<<<dim3(64, 1, 4), 256, 0, stream>>>(
      x0, 2560, 2560, W_ih0, hidden, HD, 1024, W_hh0, gates0, 14);

  // 6. LSTM cell 0 -> out hidden[0]/cell[0], h0 scratch
  k_act<<<256, 256, 0, stream>>>(gates0, b_ih0, b_hh0, cell,
                                 out + OUT_HID, out + OUT_CELL, h0, HD);

  // 7. gates1 slabs = h0 @ W_ih1^T + hidden[1] @ W_hh1^T (virtual K=2048, 32 tiles)
  gemm2<<<dim3(64, 1, 4), 256, 0, stream>>>(
      h0, HD, 1024, W_ih1, hidden + BATCH * HD, HD, 1024, W_hh1, gates1, 8);

  // 8. LSTM cell 1 -> out hidden[1]/cell[1], h1 into xfc[:, :1024]
  k_act<<<256, 256, 0, stream>>>(gates1, b_ih1, b_hh1, cell + BATCH * HD,
                                 out + OUT_HID + BATCH * HD,
                                 out + OUT_CELL + BATCH * HD, xfc, 3072);

  // 9. logits = xfc @ fc_W^T + fc_b  (direct write, reg-prefetch)
  gemm_thin<<<dim3(500, 1, 1), 256, 0, stream>>>(
      xfc, 3072, fc_W, out + OUT_LOGITS, VOCAB, fc_b, 3072);
}